// Round 1
// 855.238 us; speedup vs baseline: 1.1651x; 1.1651x over previous
//
#include <hip/hip_runtime.h>

// KroneckerLinear: out[n][8*j1+j2] = bias + sum_{i1,i2} x[n][8*i1+i2]*f1[j1][i1]*f2[j2][i2]
// Factored per-row as O = f1 · X · f2^T  (X = row viewed 8x8): 1024 MACs/row.
//
// v2: fix global coalescing. Previous version (1 thread = 1 row, lane stride
// 256 B) fragmented every wave memory op into 64 partial cache lines:
// WRITE_SIZE 851 MB vs 512 ideal, HBM stuck at 48% of peak.
// Now: 128-row tile staged through 32 KiB LDS.
//   - global->LDS via global_load_lds(16B): linear LDS dest, inverse-XOR-
//     swizzled per-lane global source (rule-21 pattern).
//   - LDS layout: chunk c of row r lives at float4-slot r*16 + (c ^ (r&15)).
//     Wave read of one chunk across 64 rows = 8 accesses/bank (optimal).
//   - 2 threads per row, split by j2-half: thread computes T_half (8x4) and
//     its 32 outputs -> total FMA/row unchanged (1024), occupancy granularity
//     doubled (32 KiB LDS -> 4-5 blocks/CU).
//   - output staged back through same LDS, stored fully coalesced.

#define GLD_TO_LDS16(gptr, lptr)                                          \
    __builtin_amdgcn_global_load_lds(                                     \
        (const __attribute__((address_space(1))) unsigned int*)(gptr),    \
        (__attribute__((address_space(3))) unsigned int*)(lptr), 16, 0, 0)

__global__ __launch_bounds__(256, 4) void kron_linear_kernel(
    const float* __restrict__ x,
    const float* __restrict__ f1,
    const float* __restrict__ f2,
    const float* __restrict__ bias,
    float* __restrict__ out,
    int n_rows)
{
    const int t = threadIdx.x;
    const long long tile_row0 = (long long)blockIdx.x * 128;

    __shared__ float4 lds[2048];  // 128 rows x 16 float4 chunks = 32 KiB

    if (tile_row0 + 128 <= (long long)n_rows) {
        // ---------------- fast path: full 128-row tile ----------------
        const int r = t & 127;   // block-local row
        const int h = t >> 7;    // j2-half (wave-uniform)

        // Stage in: coalesced global reads, inverse-swizzled source,
        // linear LDS destination (global_load_lds requirement).
        const float4* xg = (const float4*)x + tile_row0 * 16;
#pragma unroll
        for (int k = 0; k < 8; ++k) {
            int s  = k * 256 + t;          // linear LDS float4 slot
            int sr = s >> 4;               // row of this slot
            int c  = (s & 15) ^ (sr & 15); // global chunk that belongs here
            GLD_TO_LDS16(xg + (sr * 16 + c), &lds[s]);
        }
        __syncthreads();  // drains vmcnt for global_load_lds

        // Phase 1: T[i1][jj] = sum_i2 X[i1][i2] * f2[4h+jj][i2]   (8x4 half)
        const float* f2h = f2 + (h * 4) * 8;  // wave-uniform -> scalar loads
        float T[8][4];
        const int rbase = r * 16;
        const int rs = r & 15;
#pragma unroll
        for (int i1 = 0; i1 < 8; ++i1) {
            float4 a = lds[rbase + ((2 * i1)     ^ rs)];
            float4 b = lds[rbase + ((2 * i1 + 1) ^ rs)];
            float xv[8] = {a.x, a.y, a.z, a.w, b.x, b.y, b.z, b.w};
#pragma unroll
            for (int jj = 0; jj < 4; ++jj) {
                float acc = 0.f;
#pragma unroll
                for (int i2 = 0; i2 < 8; ++i2)
                    acc += xv[i2] * f2h[jj * 8 + i2];
                T[i1][jj] = acc;
            }
        }
        __syncthreads();  // all X reads done before overwriting tile

        // Phase 2: O[j1][4h+jj] = bias + sum_i1 f1[j1][i1]*T[i1][jj],
        // written swizzled into the same LDS tile.
#pragma unroll
        for (int j1 = 0; j1 < 8; ++j1) {
            float o0 = bias[j1 * 8 + 4 * h + 0];
            float o1 = bias[j1 * 8 + 4 * h + 1];
            float o2 = bias[j1 * 8 + 4 * h + 2];
            float o3 = bias[j1 * 8 + 4 * h + 3];
#pragma unroll
            for (int i1 = 0; i1 < 8; ++i1) {
                float w = f1[j1 * 8 + i1];
                o0 += w * T[i1][0];
                o1 += w * T[i1][1];
                o2 += w * T[i1][2];
                o3 += w * T[i1][3];
            }
            int c = 2 * j1 + h;  // output chunk owned by this thread
            lds[rbase + (c ^ rs)] = make_float4(o0, o1, o2, o3);
        }
        __syncthreads();

        // Stage out: linear LDS reads (conflict-free), coalesced global
        // stores (each 16-lane group covers one contiguous 256-B row).
        float4* og = (float4*)out + tile_row0 * 16;
#pragma unroll
        for (int k = 0; k < 8; ++k) {
            int s  = k * 256 + t;
            int sr = s >> 4;
            int c  = (s & 15) ^ (sr & 15);
            og[sr * 16 + c] = lds[s];
        }
    } else {
        // ---------------- slow path: partial tail tile ----------------
        // (rare; per-thread direct path, no barriers)
        long long row = tile_row0 + t;
        if (row >= (long long)n_rows) return;

        const float* xr = x + (size_t)row * 64;
        float* orow = out + (size_t)row * 64;

        float T[8][8];
#pragma unroll
        for (int i1 = 0; i1 < 8; ++i1) {
            float4 a = *(const float4*)(xr + i1 * 8);
            float4 b = *(const float4*)(xr + i1 * 8 + 4);
            float xv[8] = {a.x, a.y, a.z, a.w, b.x, b.y, b.z, b.w};
#pragma unroll
            for (int j2 = 0; j2 < 8; ++j2) {
                float acc = 0.f;
#pragma unroll
                for (int i2 = 0; i2 < 8; ++i2)
                    acc += xv[i2] * f2[j2 * 8 + i2];
                T[i1][j2] = acc;
            }
        }
#pragma unroll
        for (int j1 = 0; j1 < 8; ++j1) {
            float o[8];
#pragma unroll
            for (int j2 = 0; j2 < 8; ++j2) o[j2] = bias[j1 * 8 + j2];
#pragma unroll
            for (int i1 = 0; i1 < 8; ++i1) {
                float w = f1[j1 * 8 + i1];
#pragma unroll
                for (int j2 = 0; j2 < 8; ++j2)
                    o[j2] += w * T[i1][j2];
            }
            *(float4*)(orow + j1 * 8)     = make_float4(o[0], o[1], o[2], o[3]);
            *(float4*)(orow + j1 * 8 + 4) = make_float4(o[4], o[5], o[6], o[7]);
        }
    }
}

extern "C" void kernel_launch(void* const* d_in, const int* in_sizes, int n_in,
                              void* d_out, int out_size, void* d_ws, size_t ws_size,
                              hipStream_t stream) {
    const float* x    = (const float*)d_in[0];
    const float* f1   = (const float*)d_in[1];
    const float* f2   = (const float*)d_in[2];
    const float* bias = (const float*)d_in[3];
    float* out = (float*)d_out;

    int n_rows = out_size / 64;
    int blocks = (n_rows + 127) / 128;
    kron_linear_kernel<<<blocks, 256, 0, stream>>>(x, f1, f2, bias, out, n_rows);
}

// Round 3
// 844.284 us; speedup vs baseline: 1.1803x; 1.0130x over previous
//
#include <hip/hip_runtime.h>

// KroneckerLinear: out[n][8*j1+j2] = bias + sum_{i1,i2} x[n][8*i1+i2]*f1[j1][i1]*f2[j2][i2]
// Factored per-row as O = f1 · X · f2^T  (X = row viewed 8x8): 1024 MACs/row.
//
// v3b: v3 with the nontemporal-store type fixed (builtin requires a native
// vector type, not HIP_vector_type). Structure:
//   - 64-row tile, 16 KiB LDS -> 8 blocks/CU, 32 waves/CU (full occupancy).
//   - 4 threads/row, lane-interleaved (r=t>>2, q=t&3): the 4 owners of a row
//     are adjacent lanes of ONE wave -> wave lockstep orders phase-1 ds_reads
//     before phase-2 ds_writes; middle barrier eliminated (2 barriers/tile).
//   - global<->LDS both directions fully coalesced via the XOR swizzle:
//     chunk c of row r lives at float4-slot r*16 + (c ^ (r&15)); stage ops use
//     linear LDS slots with inverse-swizzled global addresses (rule 21).
//   - nontemporal output stores (never re-read; keep L2/L3 for input stream).

typedef float vfloat4 __attribute__((ext_vector_type(4)));  // native vec4

#define GLD_TO_LDS16(gptr, lptr)                                          \
    __builtin_amdgcn_global_load_lds(                                     \
        (const __attribute__((address_space(1))) unsigned int*)(gptr),    \
        (__attribute__((address_space(3))) unsigned int*)(lptr), 16, 0, 0)

__global__ __launch_bounds__(256, 8) void kron_linear_kernel(
    const float* __restrict__ x,
    const float* __restrict__ f1,
    const float* __restrict__ f2,
    const float* __restrict__ bias,
    float* __restrict__ out,
    int n_rows)
{
    const int t = threadIdx.x;
    const long long tile_row0 = (long long)blockIdx.x * 64;

    __shared__ vfloat4 lds[1024];  // 64 rows x 16 float4 chunks = 16 KiB

    if (tile_row0 + 64 <= (long long)n_rows) {
        // ---------------- fast path: full 64-row tile ----------------
        const int r = t >> 2;  // block-local row (0..63)
        const int q = t & 3;   // j2-quarter: this thread owns j2 in {2q, 2q+1}

        // Stage in: coalesced global reads (each 16-lane group = one
        // contiguous 256-B row, chunk-permuted), linear LDS destination.
        const vfloat4* xg = (const vfloat4*)x + tile_row0 * 16;
#pragma unroll
        for (int k = 0; k < 4; ++k) {
            int s  = k * 256 + t;          // linear LDS float4 slot
            int sr = s >> 4;               // row of this slot
            int c  = (s & 15) ^ (sr & 15); // global chunk that belongs here
            GLD_TO_LDS16(xg + (sr * 16 + c), &lds[s]);
        }
        __syncthreads();  // drains vmcnt for global_load_lds

        // Phase 1: T0/T1[i1] = sum_i2 X[i1][i2] * f2[2q+{0,1}][i2]
        const float* f2a = f2 + (2 * q) * 8;      // per-lane addr, L1-hot
        const float* f2b = f2 + (2 * q + 1) * 8;
        float T0[8], T1[8];
        const int rbase = r * 16;
        const int rs = r & 15;
#pragma unroll
        for (int i1 = 0; i1 < 8; ++i1) {
            vfloat4 a = lds[rbase + ((2 * i1)     ^ rs)];  // <=2 lanes/bank
            vfloat4 b = lds[rbase + ((2 * i1 + 1) ^ rs)];
            float xv[8] = {a.x, a.y, a.z, a.w, b.x, b.y, b.z, b.w};
            float acc0 = 0.f, acc1 = 0.f;
#pragma unroll
            for (int i2 = 0; i2 < 8; ++i2) {
                acc0 += xv[i2] * f2a[i2];
                acc1 += xv[i2] * f2b[i2];
            }
            T0[i1] = acc0;
            T1[i1] = acc1;
        }

        // No barrier: row r's 4 owners are lanes 4r..4r+3 of the SAME wave;
        // lockstep guarantees all phase-1 reads precede any phase-2 write.
        // Compiler fence so no ds_write is hoisted above a ds_read.
        asm volatile("" ::: "memory");

        // Phase 2: O[j1][2q+jj] = bias + sum_i1 f1[j1][i1]*T[i1], written
        // swizzled into the same tile as float2 halves of the output chunks.
        float2* lds2 = (float2*)lds;
#pragma unroll
        for (int j1 = 0; j1 < 8; ++j1) {
            float o0 = bias[j1 * 8 + 2 * q];
            float o1 = bias[j1 * 8 + 2 * q + 1];
#pragma unroll
            for (int i1 = 0; i1 < 8; ++i1) {
                float w = f1[j1 * 8 + i1];  // wave-uniform -> SGPR
                o0 += w * T0[i1];
                o1 += w * T1[i1];
            }
            int c = 2 * j1 + (q >> 1);  // output float4-chunk
            lds2[(rbase + (c ^ rs)) * 2 + (q & 1)] = make_float2(o0, o1);
        }
        __syncthreads();

        // Stage out: linear LDS reads, coalesced nontemporal global stores
        // (each 16-lane group covers one contiguous 256-B row, permuted).
        vfloat4* og = (vfloat4*)out + tile_row0 * 16;
#pragma unroll
        for (int k = 0; k < 4; ++k) {
            int s  = k * 256 + t;
            int sr = s >> 4;
            int c  = (s & 15) ^ (sr & 15);
            __builtin_nontemporal_store(lds[s], og + (sr * 16 + c));
        }
    } else {
        // ---------------- slow path: partial tail tile ----------------
        long long row = tile_row0 + t;
        if (row >= (long long)n_rows) return;

        const float* xr = x + (size_t)row * 64;
        float* orow = out + (size_t)row * 64;

        float T[8][8];
#pragma unroll
        for (int i1 = 0; i1 < 8; ++i1) {
            float4 a = *(const float4*)(xr + i1 * 8);
            float4 b = *(const float4*)(xr + i1 * 8 + 4);
            float xv[8] = {a.x, a.y, a.z, a.w, b.x, b.y, b.z, b.w};
#pragma unroll
            for (int j2 = 0; j2 < 8; ++j2) {
                float acc = 0.f;
#pragma unroll
                for (int i2 = 0; i2 < 8; ++i2)
                    acc += xv[i2] * f2[j2 * 8 + i2];
                T[i1][j2] = acc;
            }
        }
#pragma unroll
        for (int j1 = 0; j1 < 8; ++j1) {
            float o[8];
#pragma unroll
            for (int j2 = 0; j2 < 8; ++j2) o[j2] = bias[j1 * 8 + j2];
#pragma unroll
            for (int i1 = 0; i1 < 8; ++i1) {
                float w = f1[j1 * 8 + i1];
#pragma unroll
                for (int j2 = 0; j2 < 8; ++j2)
                    o[j2] += w * T[i1][j2];
            }
            *(float4*)(orow + j1 * 8)     = make_float4(o[0], o[1], o[2], o[3]);
            *(float4*)(orow + j1 * 8 + 4) = make_float4(o[4], o[5], o[6], o[7]);
        }
    }
}

extern "C" void kernel_launch(void* const* d_in, const int* in_sizes, int n_in,
                              void* d_out, int out_size, void* d_ws, size_t ws_size,
                              hipStream_t stream) {
    const float* x    = (const float*)d_in[0];
    const float* f1   = (const float*)d_in[1];
    const float* f2   = (const float*)d_in[2];
    const float* bias = (const float*)d_in[3];
    float* out = (float*)d_out;

    int n_rows = out_size / 64;
    int blocks = (n_rows + 63) / 64;
    kron_linear_kernel<<<blocks, 256, 0, stream>>>(x, f1, f2, bias, out, n_rows);
}